// Round 15
// baseline (102.516 us; speedup 1.0000x reference)
//
#include <hip/hip_runtime.h>
#include <hip/hip_bf16.h>

#define Bdim 2
#define Hdim 16
#define Sdim 2048
#define Ddim 64
#define NTH 32                 // 32 iterations; each does one 32-k tile per stream
#define WQ 32                  // q-rows per wave
#define NWAVE 4
#define QTILE (WQ * NWAVE)     // 128
#define QSCL (0.125f * 1.44269504088896f)   // 1/sqrt(64) * log2(e), exp2 domain
#define SCALE 0.125f
#define TBE 4096               // elems per 32-k tile buffer: K 32x64 + V 32x64
#define TVOFF 2048             // V offset within tile buffer
#define BOFF_B 12288           // stream B buffer region start (3 bufs x 4096)

typedef __bf16 bf16x8 __attribute__((ext_vector_type(8)));
typedef float  f32x4  __attribute__((ext_vector_type(4)));
typedef float  f32x16 __attribute__((ext_vector_type(16)));
typedef unsigned u32x4 __attribute__((ext_vector_type(4)));

// ---------------------------------------------------------------------------
// helpers
// ---------------------------------------------------------------------------
__device__ __forceinline__ void gll16(const __bf16* g, __bf16* l) {
  __builtin_amdgcn_global_load_lds(
      (const __attribute__((address_space(1))) void*)g,
      (__attribute__((address_space(3))) void*)l, 16, 0, 0);
}
__device__ __forceinline__ unsigned cvtpk_raw(float lo, float hi) {
  unsigned r;
  asm("v_cvt_pk_bf16_f32 %0, %1, %2" : "=v"(r) : "v"(lo), "v"(hi));
  return r;
}
template <bool SW>
__device__ __forceinline__ unsigned pko(float a, float b) {
  return SW ? cvtpk_raw(b, a) : cvtpk_raw(a, b);
}
__device__ __forceinline__ unsigned cvtpk(float a, float b, bool sw) {
  const float lo = sw ? b : a;
  const float hi = sw ? a : b;
  return cvtpk_raw(lo, hi);
}
__device__ __forceinline__ void pswap(unsigned& a, unsigned& b) {
  asm volatile("v_permlane32_swap_b32 %0, %1" : "+v"(a), "+v"(b));
}

// ---------------------------------------------------------------------------
// Fused prepass (proven at HBM floor): blocks [0,512) pack mask bits;
// blocks [512,1536) convert K fp32->bf16 and V fp32 -> Vt[bh][d][s] bf16.
// ---------------------------------------------------------------------------
__global__ __launch_bounds__(256) void prep_all(
    const void* __restrict__ mask, unsigned long long* __restrict__ packed,
    const float* __restrict__ K, const float* __restrict__ V,
    __bf16* __restrict__ Kb, __bf16* __restrict__ Vt) {
  __shared__ __bf16 tile[64][72];   // +8 pad (used by transpose half only)
  const int t = threadIdx.x;

  if (blockIdx.x < 512) {
    const int nwords = Bdim * Sdim * (Sdim / 64);
    const unsigned* m32 = (const unsigned*)mask;
    const unsigned char* m8 = (const unsigned char*)mask;
    int gid = blockIdx.x * 256 + t;
    int lane = gid & 63;
    int wid = gid >> 6;
    const int nwaves = 512 * 256 / 64;
    bool isBytes = __any(m32[lane] > 1u);   // wave-uniform dtype probe
    for (int w = wid; w < nwords; w += nwaves) {
      int v = isBytes ? (int)m8[(size_t)w * 64 + lane]
                      : (int)m32[(size_t)w * 64 + lane];
      unsigned long long bal = __ballot(v != 0);
      if (lane == 0) packed[w] = bal;
    }
    return;
  }

  const int idx = blockIdx.x - 512;
  const int bh = idx >> 5, st = idx & 31;
  const int r = t >> 2, c0 = (t & 3) << 4;
  {  // K convert, layout-preserving
    const float* ks = K + ((size_t)bh * Sdim + st * 64 + r) * Ddim + c0;
    bf16x8 o0, o1;
#pragma unroll
    for (int j = 0; j < 8; ++j) o0[j] = (__bf16)ks[j];
#pragma unroll
    for (int j = 0; j < 8; ++j) o1[j] = (__bf16)ks[8 + j];
    __bf16* kd = Kb + ((size_t)bh * Sdim + st * 64 + r) * Ddim + c0;
    *(bf16x8*)kd = o0;
    *(bf16x8*)(kd + 8) = o1;
  }
  {  // V -> LDS tile (bf16)
    const float* vs = V + ((size_t)bh * Sdim + st * 64 + r) * Ddim + c0;
#pragma unroll
    for (int j = 0; j < 16; ++j) tile[r][c0 + j] = (__bf16)vs[j];
  }
  __syncthreads();
  {  // transposed write
    const int d = t >> 2, s0 = (t & 3) << 4;
    __bf16 o[16];
#pragma unroll
    for (int j = 0; j < 16; ++j) o[j] = tile[s0 + j][d];
    __bf16* dst = Vt + ((size_t)bh * Ddim + d) * Sdim + st * 64 + s0;
    *(bf16x8*)dst = *(bf16x8*)&o[0];
    *(bf16x8*)(dst + 8) = *(bf16x8*)&o[8];
  }
}

// ---------------------------------------------------------------------------
// Main: DUAL KV-STREAM split-k flash attention. Each wave processes two
// independent 32-k tile streams per iteration (A: k in [0,1024), B: k in
// [1024,2048)) — two fully independent dependency chains (stA/stB, svA/svB,
// PV-A/PV-B) double intra-wave ILP at identical instruction totals. Shared
// otA/otB accumulators (static-max partials combine linearly). Per-stream
// 3-buffer LDS rotation, 1 barrier/iter (writer t+1 vs laggard reader t-1:
// distance 2 mod 3). 32-k tile machinery verbatim from R12 (passed);
// softmax/permlane exchange verbatim from R13 (passed).
// ---------------------------------------------------------------------------
__global__ __launch_bounds__(256, 2) void attn10(
    const float* __restrict__ Q, const __bf16* __restrict__ Kb,
    const __bf16* __restrict__ Vt,
    const unsigned long long* __restrict__ maskP, float* __restrict__ Out) {
  __shared__ alignas(16) __bf16 sm[6 * TBE];   // 48 KB: A bufs 0..2, B bufs 3..5

  const int tid = threadIdx.x;
  const int lane = tid & 63;
  const int w = tid >> 6;          // 0..3
  const int l31 = lane & 31;
  const int hi = lane >> 5;
  const int lr3 = lane >> 3;       // 0..7

  const int bid = blockIdx.x;
  const int bh = bid & 31;            // same-bh blocks share an XCD (bid%8 const)
  const int qt = bid >> 5;
  const int b = bh >> 4;
  const int qrow = qt * QTILE + w * WQ + l31;

  const __bf16* Kbase = Kb + (size_t)bh * Sdim * Ddim;
  const __bf16* Vbase = Vt + (size_t)bh * (size_t)Ddim * Sdim;
  const unsigned* mp32 =
      (const unsigned*)(maskP + ((size_t)b * Sdim + qrow) * (Sdim / 64));

  // --- probes (wave-uniform)
  const bool sw = (cvtpk_raw(0.0f, 1.0f) & 0xFFFFu) != 0u;
  bool semA;
  {
    unsigned p0 = hi ? 222u : 111u;
    unsigned p1 = hi ? 444u : 333u;
    pswap(p0, p1);
    semA = __any(hi && (p0 == 333u));
  }

  // --- Q fragments (B operand)
  bf16x8 qf[4];
  {
    const float* qs = Q + ((size_t)bh * Sdim + qrow) * Ddim;
#pragma unroll
    for (int step = 0; step < 4; ++step) {
      const int d0 = step * 16 + hi * 8;
      float4 a = *(const float4*)(qs + d0);
      float4 c = *(const float4*)(qs + d0 + 4);
      u32x4 f;
      f[0] = cvtpk(a.x * QSCL, a.y * QSCL, sw);
      f[1] = cvtpk(a.z * QSCL, a.w * QSCL, sw);
      f[2] = cvtpk(c.x * QSCL, c.y * QSCL, sw);
      f[3] = cvtpk(c.z * QSCL, c.w * QSCL, sw);
      qf[step] = __builtin_bit_cast(bf16x8, f);
    }
  }

  // --- staging constants (32-k tile; wave w covers rows/super-rows [8w,8w+8))
  const int srow = 8 * w + lr3;                 // K row in tile (0..31)
  const int sblk = (lane & 7) ^ (lr3 & 7);      // K inverse-swizzled src block
  const int vbp = (lane & 7) ^ (lr3 & 7);       // V swizzled b'
  const int vd0 = (vbp >> 2);                   // V d parity within super-row
  const int vsc = vbp & 3;                      // V source s-block
  const int dstw = w * 512;                     // LDS elem base (wave-uniform)

  // K stream bases (stream B offset by 1024 k-rows)
  const __bf16* kA = Kbase + (size_t)srow * Ddim + sblk * 8;
  const __bf16* kB = kA + (size_t)1024 * Ddim;
  // V stream bases: super-row R = 8w+lr3 holds d = 2R + vd0; stream B +1024 s
  const __bf16* vA = Vbase + (size_t)(2 * (8 * w + lr3) + vd0) * Sdim + vsc * 8;
  const __bf16* vB = vA + 1024;

#define STAGE(base_, kp_, vp_, kt_)                                         \
  do {                                                                      \
    gll16((kp_) + (size_t)(kt_) * 32 * Ddim, &sm[(base_) + dstw]);          \
    gll16((vp_) + (size_t)(kt_) * 32, &sm[(base_) + TVOFF + dstw]);         \
  } while (0)

  // --- loop-invariant frag read offsets (element offsets within a buffer)
  int kfo[4];
#pragma unroll
  for (int s = 0; s < 4; ++s)
    kfo[s] = l31 * 64 + (((s * 2 + hi) ^ (l31 & 7)) << 3);
  int vfo[2][2];
#pragma unroll
  for (int half = 0; half < 2; ++half)
#pragma unroll
    for (int ks = 0; ks < 2; ++ks)
      vfo[half][ks] = TVOFF + half * 1024 + (l31 >> 1) * 64 +
                      ((((l31 & 1) * 4 + ks * 2 + hi) ^ ((l31 >> 1) & 7)) << 3);

// QK^T of 32-k tile at buffer offset OFF -> d (f32x16)
#define QKT32(OFF, d)                                                          \
  do {                                                                         \
    __builtin_amdgcn_s_setprio(1);                                             \
    _Pragma("unroll") for (int step = 0; step < 4; ++step) {                   \
      bf16x8 kf = *(const bf16x8*)&sm[(OFF) + kfo[step]];                      \
      d = __builtin_amdgcn_mfma_f32_32x32x16_bf16(kf, qf[step], d, 0, 0, 0);   \
    }                                                                          \
    __builtin_amdgcn_s_setprio(0);                                             \
  } while (0)

// softmax + PV of a 32-k tile: S^T regs st_, u32 mask MW, buffer offset OFF
#define SMPV32(st_, MW, OFF)                                                   \
  do {                                                                         \
    float sv[16];                                                              \
    const unsigned ws_ = (~(MW)) >> (hi * 4);                                  \
    _Pragma("unroll") for (int r = 0; r < 16; ++r) {                           \
      const int cr = (r & 3) + 8 * (r >> 2);                                   \
      const float e0 = __builtin_amdgcn_exp2f(st_[r]);                         \
      const int k0 = ((int)(ws_ << (31 - cr))) >> 31;                          \
      sv[r] = __builtin_bit_cast(float, __builtin_bit_cast(int, e0) & k0);     \
    }                                                                          \
    {                                                                          \
      float s8_[8];                                                            \
      _Pragma("unroll") for (int j = 0; j < 8; ++j) s8_[j] = sv[j] + sv[j + 8];\
      lrow += ((s8_[0] + s8_[4]) + (s8_[1] + s8_[5])) +                        \
              ((s8_[2] + s8_[6]) + (s8_[3] + s8_[7]));                         \
    }                                                                          \
    unsigned pw[8];                                                            \
    _Pragma("unroll") for (int ks = 0; ks < 2; ++ks) {                         \
      const int rb = 8 * ks;                                                   \
      if (!sw) {                                                               \
        pw[ks * 4 + 0] = pko<false>(sv[rb + 0], sv[rb + 1]);                   \
        pw[ks * 4 + 1] = pko<false>(sv[rb + 2], sv[rb + 3]);                   \
        pw[ks * 4 + 2] = pko<false>(sv[rb + 4], sv[rb + 5]);                   \
        pw[ks * 4 + 3] = pko<false>(sv[rb + 6], sv[rb + 7]);                   \
      } else {                                                                 \
        pw[ks * 4 + 0] = pko<true>(sv[rb + 0], sv[rb + 1]);                    \
        pw[ks * 4 + 1] = pko<true>(sv[rb + 2], sv[rb + 3]);                    \
        pw[ks * 4 + 2] = pko<true>(sv[rb + 4], sv[rb + 5]);                    \
        pw[ks * 4 + 3] = pko<true>(sv[rb + 6], sv[rb + 7]);                    \
      }                                                                        \
    }                                                                          \
    bf16x8 pb[2];                                                              \
    _Pragma("unroll") for (int ks = 0; ks < 2; ++ks) {                         \
      unsigned W0 = pw[ks * 4 + 0], W1 = pw[ks * 4 + 1];                       \
      unsigned X0 = pw[ks * 4 + 2], X1 = pw[ks * 4 + 3];                       \
      if (semA) { pswap(W0, X0); pswap(W1, X1); }                              \
      else      { pswap(X0, W0); pswap(X1, W1); }                              \
      u32x4 wv;                                                                \
      wv[0] = W0; wv[1] = W1; wv[2] = X0; wv[3] = X1;                          \
      pb[ks] = __builtin_bit_cast(bf16x8, wv);                                 \
    }                                                                          \
    __builtin_amdgcn_s_setprio(1);                                             \
    _Pragma("unroll") for (int ks = 0; ks < 2; ++ks) {                         \
      bf16x8 vf0 = *(const bf16x8*)&sm[(OFF) + vfo[0][ks]];                    \
      otA = __builtin_amdgcn_mfma_f32_32x32x16_bf16(vf0, pb[ks], otA, 0, 0, 0);\
      bf16x8 vf1 = *(const bf16x8*)&sm[(OFF) + vfo[1][ks]];                    \
      otB = __builtin_amdgcn_mfma_f32_32x32x16_bf16(vf1, pb[ks], otB, 0, 0, 0);\
    }                                                                          \
    __builtin_amdgcn_s_setprio(0);                                             \
  } while (0)

  f32x16 otA = {0,0,0,0,0,0,0,0,0,0,0,0,0,0,0,0};
  f32x16 otB = {0,0,0,0,0,0,0,0,0,0,0,0,0,0,0,0};
  float lrow = 0.f;

  // --- prologue: masks(0) + stage tile 0 of both streams
  unsigned mwA = mp32[0], mwB = mp32[32];
  unsigned mwAn, mwBn;
  STAGE(0, kA, vA, 0);
  STAGE(BOFF_B, kB, vB, 0);
  int rdA = 0, stA_ = TBE;            // stream A: 0,4096,8192
  int rdB = BOFF_B, stB_ = BOFF_B + TBE;

#pragma unroll 1
  for (int t = 0; t < NTH; ++t) {
    if (t + 1 < NTH) {
      mwAn = mp32[t + 1];
      mwBn = mp32[32 + t + 1];
      STAGE(stA_, kA, vA, t + 1);
      STAGE(stB_, kB, vB, t + 1);
      // newest 6 vmem (2 masks + 4 glls) in flight; tile t (older) drained
      asm volatile("s_waitcnt vmcnt(6)" ::: "memory");
    } else {
      asm volatile("s_waitcnt vmcnt(0)" ::: "memory");
    }
    __builtin_amdgcn_s_barrier();
    __builtin_amdgcn_sched_barrier(0);

    // ---- two independent chains: QKT-A ∥ QKT-B, then SMPV-A ∥ SMPV-B
    f32x16 stVA = {0,0,0,0,0,0,0,0,0,0,0,0,0,0,0,0};
    f32x16 stVB = {0,0,0,0,0,0,0,0,0,0,0,0,0,0,0,0};
    QKT32(rdA, stVA);
    QKT32(rdB, stVB);
    SMPV32(stVA, mwA, rdA);
    SMPV32(stVB, mwB, rdB);

    mwA = mwAn;
    mwB = mwBn;
    rdA = stA_;
    stA_ = (stA_ == 2 * TBE) ? 0 : stA_ + TBE;
    rdB = stB_;
    stB_ = (stB_ == BOFF_B + 2 * TBE) ? BOFF_B : stB_ + TBE;
  }
#undef SMPV32
#undef QKT32
#undef STAGE

  // ---- epilogue: deferred cross-half sum reduce, then O[q][d] = O^T/l
  lrow += __shfl_xor(lrow, 32, 64);
  const float inv = 1.f / (lrow + 1e-30f);
  float* orow = Out + ((size_t)bh * Sdim + qrow) * Ddim;
#pragma unroll
  for (int g = 0; g < 4; ++g) {
    const int d0 = 8 * g + 4 * hi;
    float4 va = {otA[4 * g] * inv, otA[4 * g + 1] * inv,
                 otA[4 * g + 2] * inv, otA[4 * g + 3] * inv};
    float4 vb = {otB[4 * g] * inv, otB[4 * g + 1] * inv,
                 otB[4 * g + 2] * inv, otB[4 * g + 3] * inv};
    *(float4*)(orow + d0) = va;
    *(float4*)(orow + 32 + d0) = vb;
  }
}

// ---------------------------------------------------------------------------
// Fallback (round-1 kernel, known good): no-workspace path
// ---------------------------------------------------------------------------
__global__ __launch_bounds__(256) void attn_fallback(
    const float* __restrict__ Q, const float* __restrict__ K,
    const float* __restrict__ V, const void* __restrict__ maskRaw,
    float* __restrict__ Out) {
  __shared__ alignas(16) __bf16 Kl[64 * Ddim];
  __shared__ alignas(16) __bf16 Vts[Ddim * 64];
  __shared__ alignas(16) __bf16 Pl[4][16 * 64];

  const int tid = threadIdx.x;
  const int lane = tid & 63;
  const int w = tid >> 6;
  const int lhi = lane >> 4;
  const int llo = lane & 15;

  const int qt = blockIdx.x;
  const int bh = blockIdx.y;
  const int b = bh >> 4;
  const int qbase = qt * 64;

  const float* Qp = Q + (size_t)bh * Sdim * Ddim;
  const float* Kp = K + (size_t)bh * Sdim * Ddim;
  const float* Vp = V + (size_t)bh * Sdim * Ddim;

  bool maskBytes = __any(((const unsigned*)maskRaw)[lane] > 1u);

  bf16x8 qf0, qf1;
  {
    const int qr = qbase + w * 16 + llo;
    const float* src = Qp + (size_t)qr * Ddim + lhi * 8;
#pragma unroll
    for (int i = 0; i < 8; ++i) qf0[i] = (__bf16)(src[i] * SCALE);
#pragma unroll
    for (int i = 0; i < 8; ++i) qf1[i] = (__bf16)(src[32 + i] * SCALE);
  }

  f32x4 acc[4] = {{0.f,0.f,0.f,0.f},{0.f,0.f,0.f,0.f},
                  {0.f,0.f,0.f,0.f},{0.f,0.f,0.f,0.f}};
  float mrow[4], lrw[4];
#pragma unroll
  for (int r = 0; r < 4; ++r) { mrow[r] = -3.0e38f; lrw[r] = 0.f; }

  for (int kt = 0; kt < Sdim / 64; ++kt) {
    __syncthreads();
    {
      int r = tid >> 2;
      int c0 = (tid & 3) << 4;
      const float* ks = Kp + (size_t)(kt * 64 + r) * Ddim + c0;
      const float* vs = Vp + (size_t)(kt * 64 + r) * Ddim + c0;
      float kv[16], vv[16];
#pragma unroll
      for (int j = 0; j < 4; ++j) {
        *(float4*)(&kv[j * 4]) = *(const float4*)(ks + j * 4);
        *(float4*)(&vv[j * 4]) = *(const float4*)(vs + j * 4);
      }
      const int swzK = (r & 7) << 3;
      bf16x8 k0v, k1v;
#pragma unroll
      for (int j = 0; j < 8; ++j) { k0v[j] = (__bf16)kv[j]; k1v[j] = (__bf16)kv[8 + j]; }
      *(bf16x8*)&Kl[r * 64 + (c0 ^ swzK)] = k0v;
      *(bf16x8*)&Kl[r * 64 + ((c0 + 8) ^ swzK)] = k1v;
#pragma unroll
      for (int j = 0; j < 16; ++j) {
        int d = c0 + j;
        Vts[d * 64 + (r ^ ((d & 7) << 3))] = (__bf16)vv[j];
      }
    }
    __syncthreads();

    float sv[4][4];
#pragma unroll
    for (int cb = 0; cb < 4; ++cb) {
      int krow = cb * 16 + llo;
      int swz = (krow & 7) << 3;
      bf16x8 kf0 = *(const bf16x8*)&Kl[krow * 64 + ((lhi * 8) ^ swz)];
      bf16x8 kf1 = *(const bf16x8*)&Kl[krow * 64 + ((32 + lhi * 8) ^ swz)];
      f32x4 s = {0.f, 0.f, 0.f, 0.f};
      s = __builtin_amdgcn_mfma_f32_16x16x32_bf16(qf0, kf0, s, 0, 0, 0);
      s = __builtin_amdgcn_mfma_f32_16x16x32_bf16(qf1, kf1, s, 0, 0, 0);
#pragma unroll
      for (int r = 0; r < 4; ++r) {
        size_t q = qbase + w * 16 + lhi * 4 + r;
        size_t k = (size_t)kt * 64 + cb * 16 + llo;
        size_t idx = ((size_t)b * Sdim + q) * Sdim + k;
        bool masked = maskBytes ? (((const unsigned char*)maskRaw)[idx] != 0)
                                : (((const int*)maskRaw)[idx] != 0);
        sv[cb][r] = masked ? -1e9f : s[r];
      }
    }

    float corr[4], tsum[4];
#pragma unroll
    for (int r = 0; r < 4; ++r) {
      float mx = fmaxf(fmaxf(sv[0][r], sv[1][r]), fmaxf(sv[2][r], sv[3][r]));
#pragma unroll
      for (int off = 1; off < 16; off <<= 1)
        mx = fmaxf(mx, __shfl_xor(mx, off, 64));
      float mnew = fmaxf(mrow[r], mx);
      corr[r] = __expf(mrow[r] - mnew);
      mrow[r] = mnew;
      tsum[r] = 0.f;
    }
#pragma unroll
    for (int cb = 0; cb < 4; ++cb) {
#pragma unroll
      for (int r = 0; r < 4; ++r) {
        float p = __expf(sv[cb][r] - mrow[r]);
        tsum[r] += p;
        int row = lhi * 4 + r;
        int col = cb * 16 + llo;
        Pl[w][row * 64 + (col ^ ((row & 7) << 3))] = (__bf16)p;
      }
    }
#pragma unroll
    for (int r = 0; r < 4; ++r) {
      float s = tsum[r];
#pragma unroll
      for (int off = 1; off < 16; off <<= 1)
        s += __shfl_xor(s, off, 64);
      lrw[r] = lrw[r] * corr[r] + s;
#pragma unroll
      for (int db = 0; db < 4; ++db) acc[db][r] *= corr[r];
    }
    asm volatile("s_waitcnt lgkmcnt(0)" ::: "memory");

    bf16x8 pf0 = *(const bf16x8*)&Pl[w][llo * 64 + ((lhi * 8) ^ ((llo & 7) << 3))];
    bf16x8 pf1 = *(const bf16x8*)&Pl[w][llo * 64 + ((32 + lhi * 8) ^ ((llo & 7) << 3))];
#pragma unroll
    for (int db = 0; db < 4; ++db) {
      int d = db * 16 + llo;
      int swz = (d & 7) << 3;
      bf16x8 vf0 = *(const bf16x8*)&Vts[d * 64 + ((lhi * 8) ^ swz)];
      bf16x8 vf1 = *(const bf16x8*)&Vts[d * 64 + ((32 + lhi * 8) ^ swz)];
      acc[db] = __builtin_amdgcn_mfma_f32_16x16x32_bf16(pf0, vf0, acc[db], 0, 0, 0);
      acc[db] = __builtin_amdgcn_mfma_f32_16x16x32_bf16(pf1, vf1, acc[db], 0, 0, 0);
    }
  }

#pragma unroll
  for (int r = 0; r < 4; ++r) {
    float inv = 1.f / lrw[r];
    int q = qbase + w * 16 + lhi * 4 + r;
    float* dst = Out + ((size_t)bh * Sdim + q) * Ddim + llo;
#pragma unroll
    for (int db = 0; db < 4; ++db) dst[db * 16] = acc[db][r] * inv;
  }
}

extern "C" void kernel_launch(void* const* d_in, const int* in_sizes, int n_in,
                              void* d_out, int out_size, void* d_ws, size_t ws_size,
                              hipStream_t stream) {
  const float* Q = (const float*)d_in[0];
  const float* K = (const float*)d_in[1];
  const float* V = (const float*)d_in[2];
  const void* mask = d_in[3];
  float* out = (float*)d_out;

  const size_t packed_bytes =
      (size_t)Bdim * Sdim * (Sdim / 64) * sizeof(unsigned long long);   // 1 MiB
  const size_t tensor_bf16 = (size_t)Bdim * Hdim * Sdim * Ddim * 2;     // 8 MiB

  if (ws_size >= packed_bytes + 2 * tensor_bf16) {
    unsigned long long* packed = (unsigned long long*)d_ws;
    __bf16* Kb = (__bf16*)((char*)d_ws + packed_bytes);
    __bf16* Vt = (__bf16*)((char*)d_ws + packed_bytes + tensor_bf16);
    prep_all<<<512 + Bdim * Hdim * (Sdim / 64), 256, 0, stream>>>(
        mask, packed, K, V, Kb, Vt);
    attn10<<<(Sdim / QTILE) * Bdim * Hdim, 256, 0, stream>>>(Q, Kb, Vt, packed, out);
  } else {
    attn_fallback<<<dim3(Sdim / 64, Bdim * Hdim), 256, 0, stream>>>(Q, K, V, mask, out);
  }
}